// Round 1
// baseline (665.829 us; speedup 1.0000x reference)
//
#include <hip/hip_runtime.h>

// ---------------------------------------------------------------------------
// RoPE causal attention, B=8 S=2048 H=256, fp32 in/out, bf16 MFMA internally.
// ws layout: [0,2MB)   cos/sin table float2[2048][128]
//            [2,10MB)  Qr bf16 [b][s][h]  (pre-scaled by 1/16)
//            [10,18MB) Kr bf16 [b][s][h]
//            [18,26MB) Vt bf16 [b][h][s]  (transposed for PV B-fragments)
//            [26MB,+384KB) Wb bf16 [3][256][256] (pre-converted weights)
// ---------------------------------------------------------------------------

typedef __bf16 bf16x8 __attribute__((ext_vector_type(8)));
typedef float  f32x4  __attribute__((ext_vector_type(4)));
typedef unsigned short u16x4 __attribute__((ext_vector_type(4)));

#define LOG2E 1.44269504088896340736f
#define LOG2_10000 13.287712379549449f

__device__ __forceinline__ unsigned short f2bf(float f) {
    union { __bf16 h; unsigned short u; } cv;
    cv.h = (__bf16)f;
    return cv.u;
}

// async global->LDS, 16B per lane; LDS dest = wave-uniform base + lane*16
__device__ __forceinline__ void gl_lds16(const unsigned short* g, unsigned short* lds) {
    __builtin_amdgcn_global_load_lds(
        (const __attribute__((address_space(1))) unsigned int*)g,
        (__attribute__((address_space(3))) unsigned int*)lds, 16, 0, 0);
}

// raw barrier with compiler memory fence (no waitcnt auto-insertion), and
// counted vmcnt waits -- the T3/T4 pipeline primitives.
#define BARRIER_MEMFENCE() asm volatile("s_barrier" ::: "memory")
#define WAITVM(n) asm volatile("s_waitcnt vmcnt(" #n ")" ::: "memory")

// ---------------------------------------------------------------------------
// Kernel 1 (prep): blocks <1024 build the analytic cos/sin table; blocks
// >=1024 convert the three weight matrices to bf16 (row-major, K-contiguous).
// ---------------------------------------------------------------------------
__global__ __launch_bounds__(256) void prep(
    const float* __restrict__ wq, const float* __restrict__ wk,
    const float* __restrict__ wv,
    float2* __restrict__ cs, unsigned short* __restrict__ wb) {
    int bid = blockIdx.x;
    if (bid < 1024) {
        int id = bid * 256 + threadIdx.x;      // 0 .. 2048*128-1
        int s = id >> 7;
        int i = id & 127;
        float ex = -2.0f * ((float)i - 1.0f) * (1.0f / 256.0f);
        float theta = exp2f(LOG2_10000 * ex);
        float ang = (float)s * theta;
        float sn, c;
        sincosf(ang, &sn, &c);
        cs[id] = make_float2(c, sn);
    } else {
        int id = (bid - 1024) * 256 + threadIdx.x;   // 0 .. 49151 (float4 units)
        int sel = id >> 14;                    // 16384 float4 per 256x256 matrix
        int off = id & 16383;
        const float* src = (sel == 0) ? wq : (sel == 1) ? wk : wv;
        float4 d = ((const float4*)src)[off];
        u16x4 pk = { f2bf(d.x), f2bf(d.y), f2bf(d.z), f2bf(d.w) };
        *(u16x4*)&wb[(size_t)sel * 65536 + (size_t)off * 4] = pk;
    }
}

// ---------------------------------------------------------------------------
// Kernel 2: fused QKV projection (bf16 MFMA) + RoPE epilogue. (unchanged)
// ---------------------------------------------------------------------------
__global__ __launch_bounds__(256, 2) void qkv_rope(
    const float* __restrict__ x, const unsigned short* __restrict__ wb,
    const float2* __restrict__ cs,
    unsigned short* __restrict__ qr, unsigned short* __restrict__ kr,
    unsigned short* __restrict__ vt) {

    __shared__ unsigned short Ash[32 * 256];   // 16 KB, x tile, 32-chunk XOR swizzle
    __shared__ unsigned short Bsh[256 * 128];  // 64 KB, W half, 16-chunk XOR swizzle

    const int mt  = blockIdx.x;                // 32-row tile
    const int tid = threadIdx.x;
    const int w = tid >> 6, l = tid & 63;
    const int lane_m = l & 15, quad = l >> 4;
    const int wm = w >> 1, wn = w & 1;

    // ---- stage A once: 32 rows x 256 k, fp32 -> bf16 ----
#pragma unroll
    for (int p = 0; p < 8; ++p) {
        int id = p * 256 + tid;
        int row = id >> 6, f4 = id & 63;       // 64 float4 per row
        float4 d = *(const float4*)(x + (size_t)(mt * 32 + row) * 256 + f4 * 4);
        u16x4 pk = { f2bf(d.x), f2bf(d.y), f2bf(d.z), f2bf(d.w) };
        int k = f4 * 4;
        int idx = row * 256 + ((((k >> 3) ^ row) << 3) | (k & 7));
        *(u16x4*)&Ash[idx] = pk;
    }

    for (int sel = 0; sel < 3; ++sel) {
        f32x4 acc[8];
#pragma unroll
        for (int c = 0; c < 8; ++c) acc[c] = (f32x4){0.f, 0.f, 0.f, 0.f};

        for (int kc2 = 0; kc2 < 2; ++kc2) {    // two 128-wide k halves
            __syncthreads();                   // prior Bsh reads done (A visible)
            // stage B half: wave pass covers 4 rows (16 chunks each, XOR-16)
#pragma unroll
            for (int p = 0; p < 16; ++p) {
                int rb = (p * 4 + w) * 4;      // 4 rows per pass per wave
                int rowg = rb + (l >> 4);
                int cg = (l & 15) ^ (rowg & 15);
                gl_lds16(wb + (size_t)sel * 65536 + (size_t)rowg * 256 + kc2 * 128 + cg * 8,
                         &Bsh[rb * 128]);
            }
            __syncthreads();                   // staging drained
#pragma unroll
            for (int ks = 0; ks < 4; ++ks) {
                int ck = kc2 * 16 + ks * 4 + quad;     // 0..31 chunk along k
                int cl = ks * 4 + quad;                // 0..15 chunk within half
                int r0 = wm * 16 + lane_m;             // 0..31
                bf16x8 a0 = *(const bf16x8*)&Ash[r0 * 256 + ((ck ^ r0) << 3)];
#pragma unroll
                for (int ct = 0; ct < 8; ++ct) {
                    int nn = wn * 128 + ct * 16 + lane_m;
                    bf16x8 bb = *(const bf16x8*)&Bsh[nn * 128 + (((cl ^ (nn & 15))) << 3)];
                    acc[ct] = __builtin_amdgcn_mfma_f32_16x16x32_bf16(a0, bb, acc[ct], 0, 0, 0);
                }
            }
        }

        // ---- epilogue (no LDS use) ----
        int mbase = mt * 32 + wm * 16 + quad * 4;
        if (sel < 2) {
            unsigned short* dst = sel ? kr : qr;
            const float scale = sel ? 1.0f : 0.0625f;  // fold h^-0.5 into Q
#pragma unroll
            for (int ct = 0; ct < 8; ++ct) {
                int col = wn * 128 + ct * 16 + lane_m;
                int ii = col >> 1;
                float sgn = (col & 1) ? -1.0f : 1.0f;
#pragma unroll
                for (int rr = 0; rr < 4; ++rr) {
                    int m = mbase + rr;
                    int spos = m & 2047;
                    float2 csv = cs[spos * 128 + ii];
                    float v = acc[ct][rr];
                    float pr = __shfl_xor(v, 1);
                    float rot = (csv.x * v + sgn * csv.y * pr) * scale;
                    dst[(size_t)m * 256 + col] = f2bf(rot);
                }
            }
        } else {
#pragma unroll
            for (int ct = 0; ct < 8; ++ct) {
                int col = wn * 128 + ct * 16 + lane_m;
                u16x4 pk = { f2bf(acc[ct][0]), f2bf(acc[ct][1]),
                             f2bf(acc[ct][2]), f2bf(acc[ct][3]) };
                int bb = mbase >> 11;
                int s0 = mbase & 2047;
                *(u16x4*)&vt[((size_t)bb * 256 + col) * 2048 + s0] = pk;
            }
        }
    }
}

// ---------------------------------------------------------------------------
// Kernel 3 (REWORKED): flash attention, causal, fixed-max softmax (m=0).
// New wave split -- every LDS byte read exactly once per tile:
//   * Q: each wave holds ALL 32 q-rows x 256 in registers (qf[2][8], 64 VGPR).
//   * QK kv-split: wave w computes P[0:32][w*16..+16]  -> K tile read 1x.
//   * PV h-split:  wave w computes O[0:32][w*64..+64] over the FULL kv tile
//     -> V tile read 1x, and NO cross-wave O merge (epilogue obuf gone;
//     only a 512B l-exchange remains, since fixed-m softmax is additive).
// K and V double-buffered (2x32KB each) + Psh 4KB = 132KB LDS, 1 block/CU.
// Pipeline (3 raw barriers/tile, counted vmcnt, never 0 in steady state):
//   QK -> lgkm0+bar -> issue K(t+2) -> PV -> bar -> issue V(t+2)
//   -> vmcnt(16) [K/V(t+1) landed, t+2 in flight] -> bar
// so every staged tile has >= 1 full tile of latency cover.
// ---------------------------------------------------------------------------
__global__ __launch_bounds__(256, 1) void flash_attn(
    const unsigned short* __restrict__ qr, const unsigned short* __restrict__ kr,
    const unsigned short* __restrict__ vt, float* __restrict__ out) {

    __shared__ unsigned short Ksh[2][64 * 256];   // 2 x 32 KB
    __shared__ unsigned short Vsh[2][256 * 64];   // 2 x 32 KB
    __shared__ unsigned short Psh[32 * 64];       // 4 KB

    const int n = blockIdx.x;
    const int b = n & 7;                       // batch -> XCD L2 locality
    const int idx = n >> 3;
    const int j = (idx < 32) ? (63 - idx) : (idx - 32);   // heavy first
    const int q0 = j * 32;

    const int tid = threadIdx.x;
    const int w = tid >> 6, l = tid & 63;
    const int lane_m = l & 15, quad = l >> 4;

    // ---- Q fragments: full 32 rows x 256 k per wave ----
    bf16x8 qf[2][8];
    {
        const unsigned short* qb =
            qr + ((size_t)(b * 2048 + q0 + lane_m)) * 256 + quad * 8;
#pragma unroll
        for (int rt = 0; rt < 2; ++rt)
#pragma unroll
            for (int ks = 0; ks < 8; ++ks)
                qf[rt][ks] = *(const bf16x8*)(qb + rt * 16 * 256 + ks * 32);
    }

    const int nkt = ((q0 + 31) >> 6) + 1;

    auto stageK = [&](int kvbase, int buf) {   // 64 rows x 256, XOR-32 swizzle
#pragma unroll
        for (int p = 0; p < 8; ++p) {
            int rb = (p * 4 + w) * 2;
            int row = rb + (l >> 5);
            int cg = (l & 31) ^ (row & 31);
            gl_lds16(kr + ((size_t)(b * 2048 + kvbase + row)) * 256 + cg * 8,
                     &Ksh[buf][rb * 256]);
        }
    };
    auto stageV = [&](int kvbase, int buf) {   // 256 h x 64 kv, XOR-8 swizzle
#pragma unroll
        for (int p = 0; p < 8; ++p) {
            int hb = (p * 4 + w) * 8;
            int h = hb + (l >> 3);
            int cg = (l & 7) ^ (h & 7);
            gl_lds16(vt + ((size_t)(b * 256 + h)) * 2048 + kvbase + cg * 8,
                     &Vsh[buf][hb * 64]);
        }
    };

    // prologue: tiles 0 and 1 staged; drain once so counted waits are exact
    stageK(0, 0); stageV(0, 0);
    if (nkt > 1) { stageK(64, 1); stageV(64, 1); }
    WAITVM(0);
    BARRIER_MEMFENCE();

    f32x4 o[2][4];
#pragma unroll
    for (int rt = 0; rt < 2; ++rt)
#pragma unroll
        for (int ht = 0; ht < 4; ++ht) o[rt][ht] = (f32x4){0.f, 0.f, 0.f, 0.f};
    float l_loc[2][4] = {{0.f, 0.f, 0.f, 0.f}, {0.f, 0.f, 0.f, 0.f}};

    for (int t = 0; t < nkt; ++t) {
        const int cur = t & 1;
        const int kv0 = t * 64;

        // ---- QK: P[0:32][w*16..+16], K read once per block ----
        f32x4 sacc[2];
        sacc[0] = (f32x4){0.f, 0.f, 0.f, 0.f};
        sacc[1] = (f32x4){0.f, 0.f, 0.f, 0.f};
        const int kvr = w * 16 + lane_m;
#pragma unroll
        for (int ks = 0; ks < 8; ++ks) {
            bf16x8 bb = *(const bf16x8*)
                &Ksh[cur][kvr * 256 + (((ks * 4 + quad) ^ (kvr & 31)) << 3)];
            sacc[0] = __builtin_amdgcn_mfma_f32_16x16x32_bf16(qf[0][ks], bb, sacc[0], 0, 0, 0);
            sacc[1] = __builtin_amdgcn_mfma_f32_16x16x32_bf16(qf[1][ks], bb, sacc[1], 0, 0, 0);
        }

        // ---- exp, causal mask, P write, l accumulate ----
        const bool needmask = (kv0 + 63) > q0;     // only the diagonal tile
        const int colg = kv0 + w * 16 + lane_m;
#pragma unroll
        for (int rt = 0; rt < 2; ++rt) {
#pragma unroll
            for (int rr = 0; rr < 4; ++rr) {
                float e = exp2f(sacc[rt][rr] * LOG2E);   // m == 0
                if (needmask && colg > (q0 + rt * 16 + quad * 4 + rr)) e = 0.0f;
                l_loc[rt][rr] += e;
                int row = rt * 16 + quad * 4 + rr;
                int col = w * 16 + lane_m;
                Psh[row * 64 + ((((col >> 3) ^ (row & 7)) << 3) | (col & 7))] = f2bf(e);
            }
        }
        asm volatile("s_waitcnt lgkmcnt(0)" ::: "memory");
        BARRIER_MEMFENCE();                    // B1: P visible, K(t) consumed

        if (t + 2 < nkt) stageK(kv0 + 128, cur);   // flies over PV + tile t+1

        // ---- PV: O[0:32][w*64..+64] over full kv tile, V read once ----
#pragma unroll
        for (int ks2 = 0; ks2 < 2; ++ks2) {
            bf16x8 pa[2];
#pragma unroll
            for (int rt2 = 0; rt2 < 2; ++rt2) {
                int prow = rt2 * 16 + lane_m;
                pa[rt2] = *(const bf16x8*)
                    &Psh[prow * 64 + (((ks2 * 4 + quad) ^ (prow & 7)) << 3)];
            }
#pragma unroll
            for (int ht = 0; ht < 4; ++ht) {
                int h = w * 64 + ht * 16 + lane_m;
                bf16x8 vb = *(const bf16x8*)
                    &Vsh[cur][h * 64 + (((ks2 * 4 + quad) ^ (h & 7)) << 3)];
                o[0][ht] = __builtin_amdgcn_mfma_f32_16x16x32_bf16(pa[0], vb, o[0][ht], 0, 0, 0);
                o[1][ht] = __builtin_amdgcn_mfma_f32_16x16x32_bf16(pa[1], vb, o[1][ht], 0, 0, 0);
            }
        }
        BARRIER_MEMFENCE();                    // B2: P + V(t) consumed

        if (t + 2 < nkt) {
            stageV(kv0 + 128, cur);            // flies over tile t+1
            WAITVM(16);                        // K/V(t+1) landed; t+2 in flight
            BARRIER_MEMFENCE();                // B3: all waves' stages visible
        } else if (t + 1 < nkt) {
            WAITVM(0);                         // pipeline tail: drain t+1
            BARRIER_MEMFENCE();
        }
    }

    // ---- epilogue: l exchange (512B) + direct per-wave store, no O merge ----
    WAITVM(0);
    __syncthreads();
    float* lbuf = (float*)Psh;                 // [w][32 rows]
#pragma unroll
    for (int rt = 0; rt < 2; ++rt)
#pragma unroll
        for (int rr = 0; rr < 4; ++rr) {
            float v = l_loc[rt][rr];
            v += __shfl_xor(v, 1);
            v += __shfl_xor(v, 2);
            v += __shfl_xor(v, 4);
            v += __shfl_xor(v, 8);
            if (lane_m == 0) lbuf[w * 32 + rt * 16 + quad * 4 + rr] = v;
        }
    __syncthreads();
#pragma unroll
    for (int rt = 0; rt < 2; ++rt)
#pragma unroll
        for (int rr = 0; rr < 4; ++rr) {
            int row_l = rt * 16 + quad * 4 + rr;
            float inv = 1.0f / (lbuf[row_l] + lbuf[32 + row_l] +
                                lbuf[64 + row_l] + lbuf[96 + row_l]);
#pragma unroll
            for (int ht = 0; ht < 4; ++ht) {
                size_t idx2 = ((size_t)(b * 2048 + q0 + row_l)) * 256
                              + w * 64 + ht * 16 + lane_m;
                out[idx2] = o[rt][ht][rr] * inv;
            }
        }
}

// ---------------------------------------------------------------------------
extern "C" void kernel_launch(void* const* d_in, const int* in_sizes, int n_in,
                              void* d_out, int out_size, void* d_ws, size_t ws_size,
                              hipStream_t stream) {
    const float* x  = (const float*)d_in[0];
    const float* wq = (const float*)d_in[1];
    const float* wk = (const float*)d_in[2];
    const float* wv = (const float*)d_in[3];
    float* out = (float*)d_out;

    char* ws = (char*)d_ws;
    float2*         cs = (float2*)ws;                                  // 2 MB
    unsigned short* qr = (unsigned short*)(ws + (2u << 20));           // 8 MB
    unsigned short* kr = (unsigned short*)(ws + (10u << 20));          // 8 MB
    unsigned short* vt = (unsigned short*)(ws + (18u << 20));          // 8 MB
    unsigned short* wb = (unsigned short*)(ws + (26u << 20));          // 384 KB

    prep<<<dim3(1216), dim3(256), 0, stream>>>(wq, wk, wv, cs, wb);
    qkv_rope<<<dim3(512), dim3(256), 0, stream>>>(x, wb, cs, qr, kr, vt);
    flash_attn<<<dim3(512), dim3(256), 0, stream>>>(qr, kr, vt, out);
}